// Round 2
// baseline (1415.007 us; speedup 1.0000x reference)
//
#include <hip/hip_runtime.h>
#include <math.h>

#define BB 4
#define CC0 32
#define HH 320
#define WW 640
#define HWp (HH*WW)          // 204800
#define CHWp (CC0*HWp)       // 6553600
#define NCH (BB*HWp)         // 819200 elements per channel for BN
#define CCAT 128

// ---------------- workspace layout ----------------
// floats:  wt [0,36864)  st [36864,37184)  sc [37184,37504)
// then cat as bf16 (ushort): 104,857,600 elems = 209,715,200 B
// total ws bytes: 150016 + 209715200 = 209,865,216  (~210 MB)
#define WT_OFF  ((size_t)0)
#define ST_OFF  ((size_t)36864)
#define SC_OFF  ((size_t)37184)
#define CATF_OFF ((size_t)37504)

typedef unsigned short ushort_t;

static __device__ __forceinline__ float bf2f(ushort_t u) {
  unsigned x = ((unsigned)u) << 16;
  float f; __builtin_memcpy(&f, &x, 4); return f;
}
static __device__ __forceinline__ ushort_t f2bf(float f) {
  unsigned x; __builtin_memcpy(&x, &f, 4);
  unsigned r = (x + 0x7fffu + ((x >> 16) & 1u)) >> 16;   // RNE
  return (ushort_t)r;
}

// ---------------- block reduction helper ----------------
__device__ __forceinline__ void block_reduce2_atomic(float s, float q, float* g_s, float* g_q) {
  #pragma unroll
  for (int off = 32; off > 0; off >>= 1) {
    s += __shfl_down(s, off, 64);
    q += __shfl_down(q, off, 64);
  }
  __shared__ float ls[4], lq[4];
  int lane = threadIdx.x & 63;
  int wid  = threadIdx.x >> 6;
  if (lane == 0) { ls[wid] = s; lq[wid] = q; }
  __syncthreads();
  if (threadIdx.x == 0) {
    float ts = 0.f, tq = 0.f;
    #pragma unroll
    for (int i = 0; i < 4; ++i) { ts += ls[i]; tq += lq[i]; }
    atomicAdd(g_s, ts);
    atomicAdd(g_q, tq);
  }
}

// ---------------- 1. L2 normalize over channels (out -> d_out used as xn) ----------------
__global__ __launch_bounds__(256) void k_normalize(const float* __restrict__ x,
                                                   float* __restrict__ xn) {
  int pix = blockIdx.x * 256 + threadIdx.x;   // grid.x=800 exact
  int b   = blockIdx.y;
  const float* xp = x  + (size_t)b * CHWp + pix;
  float*       op = xn + (size_t)b * CHWp + pix;
  float v[32];
  float s = 0.f;
  #pragma unroll
  for (int c = 0; c < 32; ++c) { v[c] = xp[(size_t)c * HWp]; s += v[c] * v[c]; }
  float inv = 1.f / fmaxf(sqrtf(s), 1e-12f);
  #pragma unroll
  for (int c = 0; c < 32; ++c) op[(size_t)c * HWp] = v[c] * inv;
}

// ---------------- 2. affinity + 8->32 matmul -> bf16 cat ----------------
__global__ __launch_bounds__(256) void k_branch(const float* __restrict__ xn,
                                                const float* __restrict__ w0,
                                                const float* __restrict__ w1,
                                                const float* __restrict__ w2,
                                                const float* __restrict__ w3,
                                                ushort_t* __restrict__ cat) {
  int z = blockIdx.z;
  int d = 1 << z;                         // dil = 1,2,4,8
  const float* w = (z == 0) ? w0 : (z == 1) ? w1 : (z == 2) ? w2 : w3;
  int pix = blockIdx.x * 256 + threadIdx.x;
  int b   = blockIdx.y;
  int y = pix / WW;
  int x = pix - y * WW;

  int   ofs[8];
  float msk[8];
  {
    int kk = 0;
    #pragma unroll
    for (int i = 0; i < 3; ++i)
      #pragma unroll
      for (int j = 0; j < 3; ++j) {
        if (i == 1 && j == 1) continue;
        int dy = (i - 1) * d, dx = (j - 1) * d;
        bool ok = ((unsigned)(y + dy) < (unsigned)HH) && ((unsigned)(x + dx) < (unsigned)WW);
        ofs[kk] = ok ? (dy * WW + dx) : 0;   // invalid -> read center (in-bounds), masked below
        msk[kk] = ok ? 1.f : 0.f;
        ++kk;
      }
  }

  const float* p0 = xn + (size_t)b * CHWp + pix;
  float acc[8] = {0.f, 0.f, 0.f, 0.f, 0.f, 0.f, 0.f, 0.f};
  #pragma unroll
  for (int c = 0; c < 32; ++c) {
    const float* p = p0 + (size_t)c * HWp;
    float v = p[0];
    #pragma unroll
    for (int k = 0; k < 8; ++k) acc[k] = fmaf(v, p[ofs[k]], acc[k]);
  }
  float a[8];
  #pragma unroll
  for (int k = 0; k < 8; ++k) a[k] = fmaxf(acc[k], 0.f) * msk[k];

  ushort_t* cp = cat + ((size_t)b * CCAT + (size_t)z * 32) * HWp + pix;
  #pragma unroll
  for (int o = 0; o < 32; ++o) {
    float hv = 0.f;
    #pragma unroll
    for (int k = 0; k < 8; ++k) hv = fmaf(a[k], w[o * 8 + k], hv);
    cp[(size_t)o * HWp] = f2bf(hv);
  }
}

// ---------------- 3a. per-channel sum/sumsq over bf16 tensor ----------------
__global__ __launch_bounds__(256) void k_stats_bf16(const ushort_t* __restrict__ t,
                                                    float* __restrict__ g_s,
                                                    float* __restrict__ g_q) {
  int c = blockIdx.y, b = blockIdx.z;
  size_t base = ((size_t)b * CCAT + c) * HWp + (size_t)blockIdx.x * 8192;
  const ushort_t* p = t + base + threadIdx.x;
  float s = 0.f, q = 0.f;
  #pragma unroll
  for (int j = 0; j < 32; ++j) { float v = bf2f(p[j * 256]); s += v; q += v * v; }
  block_reduce2_atomic(s, q, g_s + c, g_q + c);
}

// ---------------- 3b. per-channel sum/sumsq over fp32 tensor ----------------
__global__ __launch_bounds__(256) void k_stats_f32(const float* __restrict__ t,
                                                   float* __restrict__ g_s,
                                                   float* __restrict__ g_q) {
  int c = blockIdx.y, b = blockIdx.z;
  size_t base = ((size_t)b * 32 + c) * HWp + (size_t)blockIdx.x * 8192;
  const float* p = t + base + threadIdx.x;
  float s = 0.f, q = 0.f;
  #pragma unroll
  for (int j = 0; j < 32; ++j) { float v = p[j * 256]; s += v; q += v * v; }
  block_reduce2_atomic(s, q, g_s + c, g_q + c);
}

// ---------------- 4. finalize BN scale/shift ----------------
__global__ void k_bnfin(const float* __restrict__ s, const float* __restrict__ q,
                        const float* g0, const float* g1, const float* g2, const float* g3,
                        const float* b0, const float* b1, const float* b2, const float* b3,
                        float* __restrict__ scale, float* __restrict__ shift, int Cc) {
  int c = threadIdx.x;
  if (c >= Cc) return;
  const float* g; const float* bb; int ci;
  if (Cc == 128) {
    int z = c >> 5; ci = c & 31;
    g  = (z == 0) ? g0 : (z == 1) ? g1 : (z == 2) ? g2 : g3;
    bb = (z == 0) ? b0 : (z == 1) ? b1 : (z == 2) ? b2 : b3;
  } else { g = g0; bb = b0; ci = c; }
  float mean = s[c] / (float)NCH;
  float var  = q[c] / (float)NCH - mean * mean;
  float inv  = 1.f / sqrtf(var + 1e-5f);
  float sc   = g[ci] * inv;
  scale[c] = sc;
  shift[c] = bb[ci] - mean * sc;
}

// ---------------- 5. transpose conv weights to [c][tap][o] ----------------
__global__ void k_wt(const float* __restrict__ wl, float* __restrict__ wt) {
  int idx = blockIdx.x * 256 + threadIdx.x;
  if (idx >= 128 * 9 * 32) return;
  int o  = idx & 31;
  int ct = idx >> 5;                 // c*9 + t
  int c  = ct / 9, t = ct - c * 9;
  wt[idx] = wl[(o * 128 + c) * 9 + t];
}

// ---------------- 6. 3x3 conv 128->32, BN+ReLU folded into staging ----------------
__global__ __launch_bounds__(256) void k_conv(const ushort_t* __restrict__ cat,
                                              const float* __restrict__ wt,
                                              const float* __restrict__ scale,
                                              const float* __restrict__ shift,
                                              float* __restrict__ out) {
  __shared__ float s_in[16][6][66];
  int tx = threadIdx.x, ty = threadIdx.y;      // block (64,4)
  int tid = ty * 64 + tx;
  int gx0 = blockIdx.x * 64, gy0 = blockIdx.y * 4;
  int b = blockIdx.z;
  float acc[32];
  #pragma unroll
  for (int o = 0; o < 32; ++o) acc[o] = 0.f;

  for (int cc = 0; cc < 8; ++cc) {
    for (int idx = tid; idx < 16 * 6 * 66; idx += 256) {
      int ci  = idx / 396;
      int rem = idx - ci * 396;
      int row = rem / 66;
      int col = rem - row * 66;
      int gy = gy0 - 1 + row, gx = gx0 - 1 + col;
      int ch = cc * 16 + ci;
      float v = 0.f;
      if ((unsigned)gy < (unsigned)HH && (unsigned)gx < (unsigned)WW) {
        float t = bf2f(cat[((size_t)b * CCAT + ch) * HWp + gy * WW + gx]);
        v = fmaxf(t * scale[ch] + shift[ch], 0.f);
      }
      s_in[ci][row][col] = v;
    }
    __syncthreads();

    const float* wchunk = wt + (size_t)cc * 16 * 9 * 32;
    for (int ci = 0; ci < 16; ++ci) {
      #pragma unroll
      for (int ky = 0; ky < 3; ++ky)
        #pragma unroll
        for (int kx = 0; kx < 3; ++kx) {
          float v = s_in[ci][ty + ky][tx + kx];
          const float* wp = wchunk + (ci * 9 + ky * 3 + kx) * 32;  // wave-uniform
          #pragma unroll
          for (int o = 0; o < 32; ++o) acc[o] = fmaf(v, wp[o], acc[o]);
        }
    }
    __syncthreads();
  }

  size_t pix = (size_t)(gy0 + ty) * WW + gx0 + tx;
  #pragma unroll
  for (int o = 0; o < 32; ++o)
    out[((size_t)b * 32 + o) * HWp + pix] = acc[o];
}

// ---------------- 7. BN2 + ReLU + 32x32 matmul, IN-PLACE on d_out ----------------
// No __restrict__: hin and out alias. Per-thread: all loads to regs, then stores,
// same pixel only -> no cross-thread hazard.
__global__ __launch_bounds__(256) void k_final(const float* hin,
                                               const float* __restrict__ wf,
                                               const float* __restrict__ scale,
                                               const float* __restrict__ shift,
                                               float* out) {
  int pix = blockIdx.x * 256 + threadIdx.x;
  int b   = blockIdx.y;
  const float* hp = hin + (size_t)b * CHWp + pix;
  float v[32];
  #pragma unroll
  for (int c = 0; c < 32; ++c)
    v[c] = fmaxf(hp[(size_t)c * HWp] * scale[c] + shift[c], 0.f);
  float r[32];
  #pragma unroll
  for (int o = 0; o < 32; ++o) {
    float s = 0.f;
    #pragma unroll
    for (int c = 0; c < 32; ++c) s = fmaf(v[c], wf[o * 32 + c], s);
    r[o] = s;
  }
  float* op = out + (size_t)b * CHWp + pix;
  #pragma unroll
  for (int o = 0; o < 32; ++o) op[(size_t)o * HWp] = r[o];
}

extern "C" void kernel_launch(void* const* d_in, const int* in_sizes, int n_in,
                              void* d_out, int out_size, void* d_ws, size_t ws_size,
                              hipStream_t stream) {
  const float* x      = (const float*)d_in[0];
  const float* w1     = (const float*)d_in[1];
  const float* g1     = (const float*)d_in[2];
  const float* b1     = (const float*)d_in[3];
  const float* w2     = (const float*)d_in[4];
  const float* g2     = (const float*)d_in[5];
  const float* b2     = (const float*)d_in[6];
  const float* w3     = (const float*)d_in[7];
  const float* g3     = (const float*)d_in[8];
  const float* b3     = (const float*)d_in[9];
  const float* w4     = (const float*)d_in[10];
  const float* g4     = (const float*)d_in[11];
  const float* b4     = (const float*)d_in[12];
  const float* w_last = (const float*)d_in[13];
  const float* g_last = (const float*)d_in[14];
  const float* b_last = (const float*)d_in[15];
  const float* w_fin  = (const float*)d_in[16];

  float* ws  = (float*)d_ws;
  float*    wt  = ws + WT_OFF;
  float*    st  = ws + ST_OFF;    // s1[128] q1[128] s2[32] q2[32]
  float*    sc  = ws + SC_OFF;    // scale1[128] shift1[128] scale2[32] shift2[32]
  ushort_t* cat = (ushort_t*)(ws + CATF_OFF);

  float* xn = (float*)d_out;      // d_out doubles as xn, then conv-out, then final out

  hipMemsetAsync(st, 0, 320 * sizeof(float), stream);

  k_normalize<<<dim3(800, 4), 256, 0, stream>>>(x, xn);
  k_branch<<<dim3(800, 4, 4), 256, 0, stream>>>(xn, w1, w2, w3, w4, cat);
  k_stats_bf16<<<dim3(25, 128, 4), 256, 0, stream>>>(cat, st, st + 128);
  k_bnfin<<<1, 128, 0, stream>>>(st, st + 128, g1, g2, g3, g4, b1, b2, b3, b4,
                                 sc, sc + 128, 128);
  k_wt<<<144, 256, 0, stream>>>(w_last, wt);
  k_conv<<<dim3(10, 80, 4), dim3(64, 4), 0, stream>>>(cat, wt, sc, sc + 128, xn);
  k_stats_f32<<<dim3(25, 32, 4), 256, 0, stream>>>(xn, st + 256, st + 288);
  k_bnfin<<<1, 128, 0, stream>>>(st + 256, st + 288, g_last, g_last, g_last, g_last,
                                 b_last, b_last, b_last, b_last, sc + 256, sc + 288, 32);
  k_final<<<dim3(800, 4), 256, 0, stream>>>(xn, w_fin, sc + 256, sc + 288, (float*)d_out);
}

// Round 3
// 1082.412 us; speedup vs baseline: 1.3073x; 1.3073x over previous
//
#include <hip/hip_runtime.h>
#include <math.h>

#define BB 4
#define CC0 32
#define HH 320
#define WW 640
#define HWp (HH*WW)          // 204800
#define CHWp (CC0*HWp)       // 6553600
#define NCH (BB*HWp)         // 819200
#define CCAT 128

// ---------------- workspace layout ----------------
// wbf (ushort, MFMA B-frag order): 36864 ushorts at float-offset 0 (73728 B)
// st  floats [36864,37184): s1[128] q1[128] s2[32] q2[32]
// sc  floats [37184,37504): scale1[128] shift1[128] scale2[32] shift2[32]
// cat bf16 channel-last [b][y][x][128]: 104,857,600 elems from float-offset 37504
#define WT_OFF  ((size_t)0)
#define ST_OFF  ((size_t)36864)
#define SC_OFF  ((size_t)37184)
#define CATF_OFF ((size_t)37504)

typedef unsigned short ushort_t;
typedef __attribute__((ext_vector_type(8)))  short  short8;
typedef __attribute__((ext_vector_type(16))) float  float16v;

static __device__ __forceinline__ float bf2f(ushort_t u) {
  unsigned x = ((unsigned)u) << 16;
  float f; __builtin_memcpy(&f, &x, 4); return f;
}
static __device__ __forceinline__ ushort_t f2bf(float f) {
  unsigned x; __builtin_memcpy(&x, &f, 4);
  unsigned r = (x + 0x7fffu + ((x >> 16) & 1u)) >> 16;   // RNE
  return (ushort_t)r;
}
static __device__ __forceinline__ unsigned pack2(float a, float b) {
  return (unsigned)f2bf(a) | ((unsigned)f2bf(b) << 16);
}

// ---------------- 1. L2 normalize over channels (writes xn into d_out) -------
__global__ __launch_bounds__(256) void k_normalize(const float* __restrict__ x,
                                                   float* __restrict__ xn) {
  int pix = blockIdx.x * 256 + threadIdx.x;
  int b   = blockIdx.y;
  const float* xp = x  + (size_t)b * CHWp + pix;
  float*       op = xn + (size_t)b * CHWp + pix;
  float v[32];
  float s = 0.f;
  #pragma unroll
  for (int c = 0; c < 32; ++c) { v[c] = xp[(size_t)c * HWp]; s += v[c] * v[c]; }
  float inv = 1.f / fmaxf(sqrtf(s), 1e-12f);
  #pragma unroll
  for (int c = 0; c < 32; ++c) op[(size_t)c * HWp] = v[c] * inv;
}

// ---------------- 2. affinity + 8->32 matmul -> bf16 cat (channel-LAST) ------
__global__ __launch_bounds__(256) void k_branch(const float* __restrict__ xn,
                                                const float* __restrict__ w0,
                                                const float* __restrict__ w1,
                                                const float* __restrict__ w2,
                                                const float* __restrict__ w3,
                                                ushort_t* __restrict__ cat) {
  int z = blockIdx.z;
  int d = 1 << z;
  const float* w = (z == 0) ? w0 : (z == 1) ? w1 : (z == 2) ? w2 : w3;
  int pix = blockIdx.x * 256 + threadIdx.x;
  int b   = blockIdx.y;
  int y = pix / WW;
  int x = pix - y * WW;

  int   ofs[8];
  float msk[8];
  {
    int kk = 0;
    #pragma unroll
    for (int i = 0; i < 3; ++i)
      #pragma unroll
      for (int j = 0; j < 3; ++j) {
        if (i == 1 && j == 1) continue;
        int dy = (i - 1) * d, dx = (j - 1) * d;
        bool ok = ((unsigned)(y + dy) < (unsigned)HH) && ((unsigned)(x + dx) < (unsigned)WW);
        ofs[kk] = ok ? (dy * WW + dx) : 0;
        msk[kk] = ok ? 1.f : 0.f;
        ++kk;
      }
  }

  const float* p0 = xn + (size_t)b * CHWp + pix;
  float acc[8] = {0.f,0.f,0.f,0.f,0.f,0.f,0.f,0.f};
  #pragma unroll
  for (int c = 0; c < 32; ++c) {
    const float* p = p0 + (size_t)c * HWp;
    float v = p[0];
    #pragma unroll
    for (int k = 0; k < 8; ++k) acc[k] = fmaf(v, p[ofs[k]], acc[k]);
  }
  float a[8];
  #pragma unroll
  for (int k = 0; k < 8; ++k) a[k] = fmaxf(acc[k], 0.f) * msk[k];

  float r[32];
  #pragma unroll
  for (int o = 0; o < 32; ++o) {
    float hv = 0.f;
    #pragma unroll
    for (int k = 0; k < 8; ++k) hv = fmaf(a[k], w[o * 8 + k], hv);
    r[o] = hv;
  }
  // channel-last store: cat[(b*HW + pix)*128 + z*32 + o], 64 B contiguous
  uint4* cp = (uint4*)(cat + ((size_t)b * HWp + pix) * 128 + z * 32);
  #pragma unroll
  for (int q = 0; q < 4; ++q) {
    uint4 u;
    u.x = pack2(r[q*8+0], r[q*8+1]);
    u.y = pack2(r[q*8+2], r[q*8+3]);
    u.z = pack2(r[q*8+4], r[q*8+5]);
    u.w = pack2(r[q*8+6], r[q*8+7]);
    cp[q] = u;
  }
}

// ---------------- 3a. per-channel stats over channel-last bf16 cat -----------
__global__ __launch_bounds__(256) void k_stats_cat(const ushort_t* __restrict__ cat,
                                                   float* __restrict__ g_s,
                                                   float* __restrict__ g_q) {
  int t = threadIdx.x;
  int ch = (t & 63) * 2;                  // each thread: 2 adjacent channels
  size_t pix0 = (size_t)blockIdx.x * 1024 + (t >> 6);
  float s0=0.f,q0=0.f,s1=0.f,q1=0.f;
  for (int j = 0; j < 256; ++j) {
    unsigned u = *(const unsigned*)&cat[(pix0 + (size_t)j*4) * 128 + ch];
    float v0 = bf2f((ushort_t)(u & 0xffff));
    float v1 = bf2f((ushort_t)(u >> 16));
    s0 += v0; q0 += v0*v0; s1 += v1; q1 += v1*v1;
  }
  __shared__ float ls0[256], lq0[256], ls1[256], lq1[256];
  ls0[t]=s0; lq0[t]=q0; ls1[t]=s1; lq1[t]=q1;
  __syncthreads();
  if (t < 64) {
    float a0=0,b0=0,a1=0,b1=0;
    #pragma unroll
    for (int k = 0; k < 4; ++k) {
      a0 += ls0[t + 64*k]; b0 += lq0[t + 64*k];
      a1 += ls1[t + 64*k]; b1 += lq1[t + 64*k];
    }
    atomicAdd(g_s + ch, a0);     atomicAdd(g_q + ch, b0);
    atomicAdd(g_s + ch + 1, a1); atomicAdd(g_q + ch + 1, b1);
  }
}

// ---------------- 3b. per-channel stats over fp32 channel-first tensor -------
__global__ __launch_bounds__(256) void k_stats_f32(const float* __restrict__ t,
                                                   float* __restrict__ g_s,
                                                   float* __restrict__ g_q) {
  int c = blockIdx.y, b = blockIdx.z;
  size_t base = ((size_t)b * 32 + c) * HWp + (size_t)blockIdx.x * 8192;
  const float* p = t + base + threadIdx.x;
  float s = 0.f, q = 0.f;
  #pragma unroll
  for (int j = 0; j < 32; ++j) { float v = p[j * 256]; s += v; q += v * v; }
  #pragma unroll
  for (int off = 32; off > 0; off >>= 1) {
    s += __shfl_down(s, off, 64);
    q += __shfl_down(q, off, 64);
  }
  __shared__ float ls[4], lq[4];
  int lane = threadIdx.x & 63, wid = threadIdx.x >> 6;
  if (lane == 0) { ls[wid] = s; lq[wid] = q; }
  __syncthreads();
  if (threadIdx.x == 0) {
    float ts=0, tq=0;
    #pragma unroll
    for (int i = 0; i < 4; ++i) { ts += ls[i]; tq += lq[i]; }
    atomicAdd(g_s + c, ts); atomicAdd(g_q + c, tq);
  }
}

// ---------------- 4. finalize BN scale/shift ----------------
__global__ void k_bnfin(const float* __restrict__ s, const float* __restrict__ q,
                        const float* g0, const float* g1, const float* g2, const float* g3,
                        const float* b0, const float* b1, const float* b2, const float* b3,
                        float* __restrict__ scale, float* __restrict__ shift, int Cc) {
  int c = threadIdx.x;
  if (c >= Cc) return;
  const float* g; const float* bb; int ci;
  if (Cc == 128) {
    int z = c >> 5; ci = c & 31;
    g  = (z == 0) ? g0 : (z == 1) ? g1 : (z == 2) ? g2 : g3;
    bb = (z == 0) ? b0 : (z == 1) ? b1 : (z == 2) ? b2 : b3;
  } else { g = g0; bb = b0; ci = c; }
  float mean = s[c] / (float)NCH;
  float var  = q[c] / (float)NCH - mean * mean;
  float inv  = 1.f / sqrtf(var + 1e-5f);
  float scv  = g[ci] * inv;
  scale[c] = scv;
  shift[c] = bb[ci] - mean * scv;
}

// ---------------- 5. weights -> bf16 MFMA B-fragment order -------------------
// wbf[((t*8 + cg)*64 + lane)*8 + j] = W[o=lane&31][ch=cg*16+(lane>>5)*8+j][tap t]
__global__ void k_wt(const float* __restrict__ wl, ushort_t* __restrict__ wbf) {
  int idx = blockIdx.x * 256 + threadIdx.x;
  if (idx >= 9 * 8 * 64 * 8) return;
  int j = idx & 7;
  int l = (idx >> 3) & 63;
  int tc = idx >> 9;                 // t*8 + cg
  int t = tc >> 3, cg = tc & 7;
  int o = l & 31;
  int ch = cg * 16 + ((l >> 5) << 3) + j;
  wbf[idx] = f2bf(wl[(o * 128 + ch) * 9 + t]);
}

// ---------------- 6. MFMA implicit-GEMM 3x3 conv 128->32 ---------------------
// block (64,4): wave w handles pixel row gy0+w, cols gx0..gx0+31
// K = (2 rounds of 64 ch) x 9 taps; A staged in LDS ch-contiguous, B from global
#define SROWS 6
#define SCOLS 34
#define CHPAD 72
__global__ __launch_bounds__(256, 4) void k_conv(const ushort_t* __restrict__ cat,
                                                 const ushort_t* __restrict__ wbf,
                                                 const float* __restrict__ scale,
                                                 const float* __restrict__ shift,
                                                 float* __restrict__ out) {
  __shared__ __align__(16) ushort_t s_in[SROWS * SCOLS * CHPAD];  // 29376 B
  int lane = threadIdx.x;            // 0..63
  int w    = threadIdx.y;            // 0..3
  int tid  = w * 64 + lane;
  int gx0 = blockIdx.x * 32, gy0 = blockIdx.y * 4;
  int b = blockIdx.z;
  size_t bHW = (size_t)b * HWp;

  const short8* wfr = (const short8*)wbf;
  float16v acc = {};

  int site0 = tid >> 3;              // 0..31
  int chp   = tid & 7;               // 16B chunk within 64 staged channels

  #pragma unroll
  for (int r = 0; r < 2; ++r) {
    // BN scale/shift for this thread's 8 channels
    int chb = r * 64 + chp * 8;
    float4 sc0 = *(const float4*)&scale[chb];
    float4 sc1 = *(const float4*)&scale[chb + 4];
    float4 sh0 = *(const float4*)&shift[chb];
    float4 sh1 = *(const float4*)&shift[chb + 4];
    float scl[8] = {sc0.x,sc0.y,sc0.z,sc0.w,sc1.x,sc1.y,sc1.z,sc1.w};
    float shf[8] = {sh0.x,sh0.y,sh0.z,sh0.w,sh1.x,sh1.y,sh1.z,sh1.w};

    if (r) __syncthreads();          // protect s_in reuse between rounds
    for (int s = site0; s < SROWS * SCOLS; s += 32) {
      int row = s / SCOLS, col = s - row * SCOLS;
      int gy = gy0 - 1 + row, gx = gx0 - 1 + col;
      uint4 u = {0u,0u,0u,0u};
      if ((unsigned)gy < (unsigned)HH && (unsigned)gx < (unsigned)WW) {
        uint4 raw = *(const uint4*)&cat[(bHW + (size_t)gy * WW + gx) * 128 + chb];
        unsigned rw[4] = {raw.x, raw.y, raw.z, raw.w};
        unsigned pk[4];
        #pragma unroll
        for (int q = 0; q < 4; ++q) {
          float v0 = fmaxf(fmaf(bf2f((ushort_t)(rw[q] & 0xffff)), scl[q*2],   shf[q*2]),   0.f);
          float v1 = fmaxf(fmaf(bf2f((ushort_t)(rw[q] >> 16)),    scl[q*2+1], shf[q*2+1]), 0.f);
          pk[q] = pack2(v0, v1);
        }
        u.x = pk[0]; u.y = pk[1]; u.z = pk[2]; u.w = pk[3];
      }
      *(uint4*)&s_in[(size_t)s * CHPAD + chp * 8] = u;
    }
    __syncthreads();

    int pcol = lane & 31;
    int half = lane >> 5;
    #pragma unroll
    for (int t = 0; t < 9; ++t) {
      int ky = t / 3, kx = t - ky * 3;
      int rowbase = ((w + ky) * SCOLS + pcol + kx) * CHPAD + half * 8;
      #pragma unroll
      for (int c = 0; c < 4; ++c) {
        short8 bfrag = wfr[(t * 8 + r * 4 + c) * 64 + lane];
        short8 afrag = *(const short8*)&s_in[rowbase + c * 16];
        acc = __builtin_amdgcn_mfma_f32_32x32x16_bf16(afrag, bfrag, acc, 0, 0, 0);
      }
    }
  }

  // epilogue: transpose C tile through LDS for coalesced channel-first stores
  __syncthreads();
  float* epi = (float*)s_in + w * (32 * 33);
  int half = lane >> 5, mm = lane & 31;
  #pragma unroll
  for (int r16 = 0; r16 < 16; ++r16) {
    int m = (r16 & 3) + 8 * (r16 >> 2) + 4 * half;
    epi[m * 33 + mm] = acc[r16];
  }
  __syncthreads();
  size_t obase = bHW + (size_t)(gy0 + w) * WW + gx0 + mm;
  #pragma unroll
  for (int i = 0; i < 16; ++i) {
    int o = half * 16 + i;
    out[(size_t)o * HWp + obase + (size_t)b * (CHWp - HWp)] = epi[mm * 33 + o];
  }
}

// ---------------- 7. BN2 + ReLU + 32x32 matmul, in-place on d_out ------------
__global__ __launch_bounds__(256) void k_final(const float* hin,
                                               const float* __restrict__ wf,
                                               const float* __restrict__ scale,
                                               const float* __restrict__ shift,
                                               float* out) {
  int pix = blockIdx.x * 256 + threadIdx.x;
  int b   = blockIdx.y;
  const float* hp = hin + (size_t)b * CHWp + pix;
  float v[32];
  #pragma unroll
  for (int c = 0; c < 32; ++c)
    v[c] = fmaxf(hp[(size_t)c * HWp] * scale[c] + shift[c], 0.f);
  float r[32];
  #pragma unroll
  for (int o = 0; o < 32; ++o) {
    float s = 0.f;
    #pragma unroll
    for (int c = 0; c < 32; ++c) s = fmaf(v[c], wf[o * 32 + c], s);
    r[o] = s;
  }
  float* op = out + (size_t)b * CHWp + pix;
  #pragma unroll
  for (int o = 0; o < 32; ++o) op[(size_t)o * HWp] = r[o];
}

extern "C" void kernel_launch(void* const* d_in, const int* in_sizes, int n_in,
                              void* d_out, int out_size, void* d_ws, size_t ws_size,
                              hipStream_t stream) {
  const float* x      = (const float*)d_in[0];
  const float* w1     = (const float*)d_in[1];
  const float* g1     = (const float*)d_in[2];
  const float* b1     = (const float*)d_in[3];
  const float* w2     = (const float*)d_in[4];
  const float* g2     = (const float*)d_in[5];
  const float* b2     = (const float*)d_in[6];
  const float* w3     = (const float*)d_in[7];
  const float* g3     = (const float*)d_in[8];
  const float* b3     = (const float*)d_in[9];
  const float* w4     = (const float*)d_in[10];
  const float* g4     = (const float*)d_in[11];
  const float* b4     = (const float*)d_in[12];
  const float* w_last = (const float*)d_in[13];
  const float* g_last = (const float*)d_in[14];
  const float* b_last = (const float*)d_in[15];
  const float* w_fin  = (const float*)d_in[16];

  float* ws = (float*)d_ws;
  ushort_t* wbf = (ushort_t*)(ws + WT_OFF);
  float*    st  = ws + ST_OFF;
  float*    sc  = ws + SC_OFF;
  ushort_t* cat = (ushort_t*)(ws + CATF_OFF);

  float* xn = (float*)d_out;   // d_out: xn -> conv-out -> final out

  hipMemsetAsync(st, 0, 320 * sizeof(float), stream);

  k_normalize<<<dim3(800, 4), 256, 0, stream>>>(x, xn);
  k_branch<<<dim3(800, 4, 4), 256, 0, stream>>>(xn, w1, w2, w3, w4, cat);
  k_stats_cat<<<800, 256, 0, stream>>>(cat, st, st + 128);
  k_bnfin<<<1, 128, 0, stream>>>(st, st + 128, g1, g2, g3, g4, b1, b2, b3, b4,
                                 sc, sc + 128, 128);
  k_wt<<<144, 256, 0, stream>>>(w_last, wbf);
  k_conv<<<dim3(20, 80, 4), dim3(64, 4), 0, stream>>>(cat, wbf, sc, sc + 128, xn);
  k_stats_f32<<<dim3(25, 32, 4), 256, 0, stream>>>(xn, st + 256, st + 288);
  k_bnfin<<<1, 128, 0, stream>>>(st + 256, st + 288, g_last, g_last, g_last, g_last,
                                 b_last, b_last, b_last, b_last, sc + 256, sc + 288, 32);
  k_final<<<dim3(800, 4), 256, 0, stream>>>(xn, w_fin, sc + 256, sc + 288, (float*)d_out);
}

// Round 4
// 649.117 us; speedup vs baseline: 2.1799x; 1.6675x over previous
//
#include <hip/hip_runtime.h>
#include <math.h>

#define BB 4
#define CC0 32
#define HH 320
#define WW 640
#define HWp (HH*WW)          // 204800
#define CHWp (CC0*HWp)       // 6553600
#define NCH (BB*HWp)         // 819200
#define CCAT 128

// ---------------- workspace layout ----------------
// wbf (ushort, MFMA B-frag order): 36864 ushorts at float-offset 0 (73728 B)
// st  floats [36864,37184): s1[128] q1[128] s2[32] q2[32]
// sc  floats [37184,37504): scale1[128] shift1[128] scale2[32] shift2[32]
// cat bf16 channel-last [b][pix][128]: 104,857,600 elems from float-offset 37504
#define WT_OFF  ((size_t)0)
#define ST_OFF  ((size_t)36864)
#define SC_OFF  ((size_t)37184)
#define CATF_OFF ((size_t)37504)

typedef unsigned short ushort_t;
typedef __attribute__((ext_vector_type(8)))  short  short8;
typedef __attribute__((ext_vector_type(16))) float  float16v;

static __device__ __forceinline__ float bf2f(ushort_t u) {
  unsigned x = ((unsigned)u) << 16;
  float f; __builtin_memcpy(&f, &x, 4); return f;
}
static __device__ __forceinline__ ushort_t f2bf(float f) {
  unsigned x; __builtin_memcpy(&x, &f, 4);
  unsigned r = (x + 0x7fffu + ((x >> 16) & 1u)) >> 16;   // RNE
  return (ushort_t)r;
}
static __device__ __forceinline__ unsigned pack2(float a, float b) {
  return (unsigned)f2bf(a) | ((unsigned)f2bf(b) << 16);
}
static __device__ __forceinline__ void unpack8(uint4 u, float* f) {
  f[0] = bf2f((ushort_t)(u.x & 0xffff)); f[1] = bf2f((ushort_t)(u.x >> 16));
  f[2] = bf2f((ushort_t)(u.y & 0xffff)); f[3] = bf2f((ushort_t)(u.y >> 16));
  f[4] = bf2f((ushort_t)(u.z & 0xffff)); f[5] = bf2f((ushort_t)(u.z >> 16));
  f[6] = bf2f((ushort_t)(u.w & 0xffff)); f[7] = bf2f((ushort_t)(u.w >> 16));
}

// ---------------- 1. L2 normalize -> bf16 channel-LAST xn (into d_out) -------
__global__ __launch_bounds__(256) void k_normalize(const float* __restrict__ x,
                                                   ushort_t* __restrict__ xnb) {
  int pix = blockIdx.x * 256 + threadIdx.x;
  int b   = blockIdx.y;
  const float* xp = x + (size_t)b * CHWp + pix;
  float v[32];
  float s = 0.f;
  #pragma unroll
  for (int c = 0; c < 32; ++c) { v[c] = xp[(size_t)c * HWp]; s += v[c] * v[c]; }
  float inv = 1.f / fmaxf(sqrtf(s), 1e-12f);
  uint4* op = (uint4*)(xnb + ((size_t)b * HWp + pix) * 32);
  #pragma unroll
  for (int q = 0; q < 4; ++q) {
    uint4 u;
    u.x = pack2(v[q*8+0]*inv, v[q*8+1]*inv);
    u.y = pack2(v[q*8+2]*inv, v[q*8+3]*inv);
    u.z = pack2(v[q*8+4]*inv, v[q*8+5]*inv);
    u.w = pack2(v[q*8+6]*inv, v[q*8+7]*inv);
    op[q] = u;
  }
}

// ---------------- 2. affinity + 8->32 matmul -> bf16 cat (channel-last) ------
__global__ __launch_bounds__(256) void k_branch(const ushort_t* __restrict__ xnb,
                                                const float* __restrict__ w0,
                                                const float* __restrict__ w1,
                                                const float* __restrict__ w2,
                                                const float* __restrict__ w3,
                                                ushort_t* __restrict__ cat) {
  int z = blockIdx.z;
  int d = 1 << z;
  const float* w = (z == 0) ? w0 : (z == 1) ? w1 : (z == 2) ? w2 : w3;
  int pix = blockIdx.x * 256 + threadIdx.x;
  int b   = blockIdx.y;
  int y = pix / WW;
  int x = pix - y * WW;

  int   ofs[8];
  float msk[8];
  {
    int kk = 0;
    #pragma unroll
    for (int i = 0; i < 3; ++i)
      #pragma unroll
      for (int j = 0; j < 3; ++j) {
        if (i == 1 && j == 1) continue;
        int dy = (i - 1) * d, dx = (j - 1) * d;
        bool ok = ((unsigned)(y + dy) < (unsigned)HH) && ((unsigned)(x + dx) < (unsigned)WW);
        ofs[kk] = ok ? (dy * WW + dx) : 0;    // OOB -> read own pixel (in-bounds), masked
        msk[kk] = ok ? 1.f : 0.f;
        ++kk;
      }
  }

  const ushort_t* cp0 = xnb + ((size_t)b * HWp + pix) * 32;
  const uint4* cv = (const uint4*)cp0;
  float cen[32];
  {
    uint4 c0 = cv[0], c1 = cv[1], c2 = cv[2], c3 = cv[3];
    unpack8(c0, cen); unpack8(c1, cen + 8); unpack8(c2, cen + 16); unpack8(c3, cen + 24);
  }

  float acc[8] = {0.f,0.f,0.f,0.f,0.f,0.f,0.f,0.f};
  #pragma unroll
  for (int k = 0; k < 8; ++k) {
    const uint4* np = (const uint4*)(cp0 + (ptrdiff_t)ofs[k] * 32);
    uint4 n0 = np[0], n1 = np[1], n2 = np[2], n3 = np[3];
    float nb[32];
    unpack8(n0, nb); unpack8(n1, nb + 8); unpack8(n2, nb + 16); unpack8(n3, nb + 24);
    float a = 0.f;
    #pragma unroll
    for (int c = 0; c < 32; ++c) a = fmaf(cen[c], nb[c], a);
    acc[k] = a;
  }
  float a[8];
  #pragma unroll
  for (int k = 0; k < 8; ++k) a[k] = fmaxf(acc[k], 0.f) * msk[k];

  float r[32];
  #pragma unroll
  for (int o = 0; o < 32; ++o) {
    float hv = 0.f;
    #pragma unroll
    for (int k = 0; k < 8; ++k) hv = fmaf(a[k], w[o * 8 + k], hv);
    r[o] = hv;
  }
  uint4* cp = (uint4*)(cat + ((size_t)b * HWp + pix) * 128 + z * 32);
  #pragma unroll
  for (int q = 0; q < 4; ++q) {
    uint4 u;
    u.x = pack2(r[q*8+0], r[q*8+1]);
    u.y = pack2(r[q*8+2], r[q*8+3]);
    u.z = pack2(r[q*8+4], r[q*8+5]);
    u.w = pack2(r[q*8+6], r[q*8+7]);
    cp[q] = u;
  }
}

// ---------------- 3a. per-channel stats over channel-last bf16 cat -----------
__global__ __launch_bounds__(256) void k_stats_cat(const ushort_t* __restrict__ cat,
                                                   float* __restrict__ g_s,
                                                   float* __restrict__ g_q) {
  int t = threadIdx.x;
  int ch = (t & 63) * 2;                  // each thread: 2 adjacent channels
  size_t pix0 = (size_t)blockIdx.x * 1024 + (t >> 6);
  float s0=0.f,q0=0.f,s1=0.f,q1=0.f;
  for (int j = 0; j < 256; ++j) {
    unsigned u = *(const unsigned*)&cat[(pix0 + (size_t)j*4) * 128 + ch];
    float v0 = bf2f((ushort_t)(u & 0xffff));
    float v1 = bf2f((ushort_t)(u >> 16));
    s0 += v0; q0 += v0*v0; s1 += v1; q1 += v1*v1;
  }
  __shared__ float ls0[256], lq0[256], ls1[256], lq1[256];
  ls0[t]=s0; lq0[t]=q0; ls1[t]=s1; lq1[t]=q1;
  __syncthreads();
  if (t < 64) {
    float a0=0,b0=0,a1=0,b1=0;
    #pragma unroll
    for (int k = 0; k < 4; ++k) {
      a0 += ls0[t + 64*k]; b0 += lq0[t + 64*k];
      a1 += ls1[t + 64*k]; b1 += lq1[t + 64*k];
    }
    atomicAdd(g_s + ch, a0);     atomicAdd(g_q + ch, b0);
    atomicAdd(g_s + ch + 1, a1); atomicAdd(g_q + ch + 1, b1);
  }
}

// ---------------- 3b. per-channel stats over fp32 channel-first tensor -------
__global__ __launch_bounds__(256) void k_stats_f32(const float* __restrict__ t,
                                                   float* __restrict__ g_s,
                                                   float* __restrict__ g_q) {
  int c = blockIdx.y, b = blockIdx.z;
  size_t base = ((size_t)b * 32 + c) * HWp + (size_t)blockIdx.x * 8192;
  const float* p = t + base + threadIdx.x;
  float s = 0.f, q = 0.f;
  #pragma unroll
  for (int j = 0; j < 32; ++j) { float v = p[j * 256]; s += v; q += v * v; }
  #pragma unroll
  for (int off = 32; off > 0; off >>= 1) {
    s += __shfl_down(s, off, 64);
    q += __shfl_down(q, off, 64);
  }
  __shared__ float ls[4], lq[4];
  int lane = threadIdx.x & 63, wid = threadIdx.x >> 6;
  if (lane == 0) { ls[wid] = s; lq[wid] = q; }
  __syncthreads();
  if (threadIdx.x == 0) {
    float ts=0, tq=0;
    #pragma unroll
    for (int i = 0; i < 4; ++i) { ts += ls[i]; tq += lq[i]; }
    atomicAdd(g_s + c, ts); atomicAdd(g_q + c, tq);
  }
}

// ---------------- 4. finalize BN scale/shift ----------------
__global__ void k_bnfin(const float* __restrict__ s, const float* __restrict__ q,
                        const float* g0, const float* g1, const float* g2, const float* g3,
                        const float* b0, const float* b1, const float* b2, const float* b3,
                        float* __restrict__ scale, float* __restrict__ shift, int Cc) {
  int c = threadIdx.x;
  if (c >= Cc) return;
  const float* g; const float* bb; int ci;
  if (Cc == 128) {
    int z = c >> 5; ci = c & 31;
    g  = (z == 0) ? g0 : (z == 1) ? g1 : (z == 2) ? g2 : g3;
    bb = (z == 0) ? b0 : (z == 1) ? b1 : (z == 2) ? b2 : b3;
  } else { g = g0; bb = b0; ci = c; }
  float mean = s[c] / (float)NCH;
  float var  = q[c] / (float)NCH - mean * mean;
  float inv  = 1.f / sqrtf(var + 1e-5f);
  float scv  = g[ci] * inv;
  scale[c] = scv;
  shift[c] = bb[ci] - mean * scv;
}

// ---------------- 5. weights -> bf16 MFMA B-fragment order -------------------
// wbf[((t*8 + cg)*64 + lane)*8 + j] = W[o=lane&31][ch=cg*16+(lane>>5)*8+j][tap t]
__global__ void k_wt(const float* __restrict__ wl, ushort_t* __restrict__ wbf) {
  int idx = blockIdx.x * 256 + threadIdx.x;
  if (idx >= 9 * 8 * 64 * 8) return;
  int j = idx & 7;
  int l = (idx >> 3) & 63;
  int tc = idx >> 9;                 // t*8 + cg
  int t = tc >> 3, cg = tc & 7;
  int o = l & 31;
  int ch = cg * 16 + ((l >> 5) << 3) + j;
  wbf[idx] = f2bf(wl[(o * 128 + ch) * 9 + t]);
}

// ---------------- 6. MFMA implicit-GEMM 3x3 conv 128->32 ---------------------
#define SROWS 6
#define SCOLS 34
#define CHPAD 72
__global__ __launch_bounds__(256, 4) void k_conv(const ushort_t* __restrict__ cat,
                                                 const ushort_t* __restrict__ wbf,
                                                 const float* __restrict__ scale,
                                                 const float* __restrict__ shift,
                                                 float* __restrict__ out) {
  __shared__ __align__(16) ushort_t s_in[SROWS * SCOLS * CHPAD];  // 29376 B
  int lane = threadIdx.x;            // 0..63
  int w    = threadIdx.y;            // 0..3
  int tid  = w * 64 + lane;
  int gx0 = blockIdx.x * 32, gy0 = blockIdx.y * 4;
  int b = blockIdx.z;
  size_t bHW = (size_t)b * HWp;

  const short8* wfr = (const short8*)wbf;
  float16v acc = {};

  int site0 = tid >> 3;              // 0..31
  int chp   = tid & 7;               // 16B chunk within 64 staged channels

  #pragma unroll
  for (int r = 0; r < 2; ++r) {
    int chb = r * 64 + chp * 8;
    float4 sc0 = *(const float4*)&scale[chb];
    float4 sc1 = *(const float4*)&scale[chb + 4];
    float4 sh0 = *(const float4*)&shift[chb];
    float4 sh1 = *(const float4*)&shift[chb + 4];
    float scl[8] = {sc0.x,sc0.y,sc0.z,sc0.w,sc1.x,sc1.y,sc1.z,sc1.w};
    float shf[8] = {sh0.x,sh0.y,sh0.z,sh0.w,sh1.x,sh1.y,sh1.z,sh1.w};

    if (r) __syncthreads();
    for (int s = site0; s < SROWS * SCOLS; s += 32) {
      int row = s / SCOLS, col = s - row * SCOLS;
      int gy = gy0 - 1 + row, gx = gx0 - 1 + col;
      uint4 u = {0u,0u,0u,0u};
      if ((unsigned)gy < (unsigned)HH && (unsigned)gx < (unsigned)WW) {
        uint4 raw = *(const uint4*)&cat[(bHW + (size_t)gy * WW + gx) * 128 + chb];
        unsigned rw[4] = {raw.x, raw.y, raw.z, raw.w};
        unsigned pk[4];
        #pragma unroll
        for (int q = 0; q < 4; ++q) {
          float v0 = fmaxf(fmaf(bf2f((ushort_t)(rw[q] & 0xffff)), scl[q*2],   shf[q*2]),   0.f);
          float v1 = fmaxf(fmaf(bf2f((ushort_t)(rw[q] >> 16)),    scl[q*2+1], shf[q*2+1]), 0.f);
          pk[q] = pack2(v0, v1);
        }
        u.x = pk[0]; u.y = pk[1]; u.z = pk[2]; u.w = pk[3];
      }
      *(uint4*)&s_in[(size_t)s * CHPAD + chp * 8] = u;
    }
    __syncthreads();

    int pcol = lane & 31;
    int half = lane >> 5;
    #pragma unroll
    for (int t = 0; t < 9; ++t) {
      int ky = t / 3, kx = t - ky * 3;
      int rowbase = ((w + ky) * SCOLS + pcol + kx) * CHPAD + half * 8;
      #pragma unroll
      for (int c = 0; c < 4; ++c) {
        short8 bfrag = wfr[(t * 8 + r * 4 + c) * 64 + lane];
        short8 afrag = *(const short8*)&s_in[rowbase + c * 16];
        acc = __builtin_amdgcn_mfma_f32_32x32x16_bf16(afrag, bfrag, acc, 0, 0, 0);
      }
    }
  }

  // epilogue: transpose C tile through LDS for coalesced channel-first stores
  __syncthreads();
  float* epi = (float*)s_in + w * (32 * 33);
  int half = lane >> 5, mm = lane & 31;
  #pragma unroll
  for (int r16 = 0; r16 < 16; ++r16) {
    int m = (r16 & 3) + 8 * (r16 >> 2) + 4 * half;
    epi[m * 33 + mm] = acc[r16];
  }
  __syncthreads();
  size_t obase = bHW + (size_t)(gy0 + w) * WW + gx0 + mm;
  #pragma unroll
  for (int i = 0; i < 16; ++i) {
    int o = half * 16 + i;
    out[(size_t)o * HWp + obase + (size_t)b * (CHWp - HWp)] = epi[mm * 33 + o];
  }
}

// ---------------- 7. BN2 + ReLU + 32x32 matmul, in-place on d_out ------------
__global__ __launch_bounds__(256) void k_final(const float* hin,
                                               const float* __restrict__ wf,
                                               const float* __restrict__ scale,
                                               const float* __restrict__ shift,
                                               float* out) {
  int pix = blockIdx.x * 256 + threadIdx.x;
  int b   = blockIdx.y;
  const float* hp = hin + (size_t)b * CHWp + pix;
  float v[32];
  #pragma unroll
  for (int c = 0; c < 32; ++c)
    v[c] = fmaxf(hp[(size_t)c * HWp] * scale[c] + shift[c], 0.f);
  float r[32];
  #pragma unroll
  for (int o = 0; o < 32; ++o) {
    float s = 0.f;
    #pragma unroll
    for (int c = 0; c < 32; ++c) s = fmaf(v[c], wf[o * 32 + c], s);
    r[o] = s;
  }
  float* op = out + (size_t)b * CHWp + pix;
  #pragma unroll
  for (int o = 0; o < 32; ++o) op[(size_t)o * HWp] = r[o];
}

extern "C" void kernel_launch(void* const* d_in, const int* in_sizes, int n_in,
                              void* d_out, int out_size, void* d_ws, size_t ws_size,
                              hipStream_t stream) {
  const float* x      = (const float*)d_in[0];
  const float* w1     = (const float*)d_in[1];
  const float* g1     = (const float*)d_in[2];
  const float* b1     = (const float*)d_in[3];
  const float* w2     = (const float*)d_in[4];
  const float* g2     = (const float*)d_in[5];
  const float* b2     = (const float*)d_in[6];
  const float* w3     = (const float*)d_in[7];
  const float* g3     = (const float*)d_in[8];
  const float* b3     = (const float*)d_in[9];
  const float* w4     = (const float*)d_in[10];
  const float* g4     = (const float*)d_in[11];
  const float* b4     = (const float*)d_in[12];
  const float* w_last = (const float*)d_in[13];
  const float* g_last = (const float*)d_in[14];
  const float* b_last = (const float*)d_in[15];
  const float* w_fin  = (const float*)d_in[16];

  float* ws = (float*)d_ws;
  ushort_t* wbf = (ushort_t*)(ws + WT_OFF);
  float*    st  = ws + ST_OFF;
  float*    sc  = ws + SC_OFF;
  ushort_t* cat = (ushort_t*)(ws + CATF_OFF);

  ushort_t* xnb = (ushort_t*)d_out;  // d_out: bf16 xn -> fp32 conv-out -> final out
  float*    xn  = (float*)d_out;

  hipMemsetAsync(st, 0, 320 * sizeof(float), stream);

  k_normalize<<<dim3(800, 4), 256, 0, stream>>>(x, xnb);
  k_branch<<<dim3(800, 4, 4), 256, 0, stream>>>(xnb, w1, w2, w3, w4, cat);
  k_stats_cat<<<800, 256, 0, stream>>>(cat, st, st + 128);
  k_bnfin<<<1, 128, 0, stream>>>(st, st + 128, g1, g2, g3, g4, b1, b2, b3, b4,
                                 sc, sc + 128, 128);
  k_wt<<<144, 256, 0, stream>>>(w_last, wbf);
  k_conv<<<dim3(20, 80, 4), dim3(64, 4), 0, stream>>>(cat, wbf, sc, sc + 128, xn);
  k_stats_f32<<<dim3(25, 32, 4), 256, 0, stream>>>(xn, st + 256, st + 288);
  k_bnfin<<<1, 128, 0, stream>>>(st + 256, st + 288, g_last, g_last, g_last, g_last,
                                 b_last, b_last, b_last, b_last, sc + 256, sc + 288, 32);
  k_final<<<dim3(800, 4), 256, 0, stream>>>(xn, w_fin, sc + 256, sc + 288, (float*)d_out);
}